// Round 7
// baseline (44.949 us; speedup 1.0000x reference)
//
#include <hip/hip_runtime.h>

#define N_DOCS 500000
#define N_WORDS 100000
#define EMB 128
#define BATCH 16384
#define CTX 8
#define K 6
#define TBLK 12500  // transpose blocks: 3125 word-tiles x 4 dim-tiles
#define XBLK (BATCH / 4)

__device__ __forceinline__ unsigned short f2bf(float f) {
    unsigned u = __float_as_uint(f);
    unsigned r = u + 0x7fffu + ((u >> 16) & 1u);  // round-to-nearest-even
    return (unsigned short)(r >> 16);
}
#define BF2F(h) __uint_as_float(((unsigned)(h)) << 16)

// ---------------------------------------------------------------------------
// Mega-kernel: blocks [0,TBLK) transpose Wp f32 -> WpT bf16 (32x32 LDS tiles);
// blocks [TBLK, TBLK+XBLK) compute x[b] = D[doc[b]] + sum_c W[ctx[b,c]].
// The two block families are independent -> their memory phases overlap.
// ---------------------------------------------------------------------------
__global__ __launch_bounds__(256) void mega(const float* __restrict__ Wp,
                                            unsigned short* __restrict__ WpT,
                                            const float* __restrict__ D,
                                            const float* __restrict__ W,
                                            const int* __restrict__ ctx_ids,
                                            const int* __restrict__ doc_ids,
                                            float* __restrict__ x) {
    const int bid = blockIdx.x;
    if (bid < TBLK) {
        __shared__ float tile[32][33];
        const int ctile = bid % 3125;          // word tile
        const int rtile = bid / 3125;          // dim tile
        const int tx = threadIdx.x & 31, ty = threadIdx.x >> 5;  // (32, 8)
        const int col = ctile * 32 + tx;
#pragma unroll
        for (int j = 0; j < 4; ++j)
            tile[ty + 8 * j][tx] = Wp[(size_t)(rtile * 32 + ty + 8 * j) * N_WORDS + col];
        __syncthreads();
#pragma unroll
        for (int j = 0; j < 4; ++j) {
            const int r = ty + 8 * j;  // word within tile
            WpT[(size_t)(ctile * 32 + r) * EMB + rtile * 32 + tx] = f2bf(tile[tx][r]);
        }
    } else {
        const int lane = threadIdx.x & 63;
        const int b = __builtin_amdgcn_readfirstlane((bid - TBLK) * 4 + (threadIdx.x >> 6));
        float2 xx = ((const float2*)(D + (size_t)doc_ids[b] * EMB))[lane];
#pragma unroll
        for (int c = 0; c < CTX; ++c) {
            const float2 w2 = ((const float2*)(W + (size_t)ctx_ids[b * CTX + c] * EMB))[lane];
            xx.x += w2.x;
            xx.y += w2.y;
        }
        ((float2*)(x + (size_t)b * EMB))[lane] = xx;
    }
}

// ---------------------------------------------------------------------------
// Dot kernel: one wave per pair p = b*K + k. Short chain, 98304 waves.
// Lane l holds dims {2l, 2l+1}. x row 512B + WpT row 256B, both coalesced.
// ---------------------------------------------------------------------------
__global__ __launch_bounds__(256) void dotk(const unsigned short* __restrict__ WpT,
                                            const float* __restrict__ x,
                                            const int* __restrict__ tn,
                                            float* __restrict__ out) {
    const int lane = threadIdx.x & 63;
    const int p = __builtin_amdgcn_readfirstlane(blockIdx.x * 4 + (threadIdx.x >> 6));
    const int id = tn[p];
    const int b = (int)((unsigned)p / 6u);
    const float2 xv = ((const float2*)(x + (size_t)b * EMB))[lane];
    const ushort2 w2 = ((const ushort2*)(WpT + (size_t)id * EMB))[lane];
    float s = xv.x * BF2F(w2.x) + xv.y * BF2F(w2.y);
#pragma unroll
    for (int off = 32; off > 0; off >>= 1) s += __shfl_xor(s, off, 64);
    if (lane == 0) out[p] = s;
}

// ---------------------------------------------------------------------------
// Fallback (no workspace): direct strided column gather.
// ---------------------------------------------------------------------------
__global__ __launch_bounds__(256) void nce_direct(
    const float* __restrict__ D, const float* __restrict__ W,
    const float* __restrict__ Wp, const int* __restrict__ ctx_ids,
    const int* __restrict__ doc_ids, const int* __restrict__ tn_ids,
    float* __restrict__ out) {
    const int wave = threadIdx.x >> 6, lane = threadIdx.x & 63;
    const int b = blockIdx.x * 4 + wave;
    if (b >= BATCH) return;
    float2 xx = ((const float2*)(D + (size_t)doc_ids[b] * EMB))[lane];
#pragma unroll
    for (int c = 0; c < CTX; ++c) {
        const float2 w2 = ((const float2*)(W + (size_t)ctx_ids[b * CTX + c] * EMB))[lane];
        xx.x += w2.x;
        xx.y += w2.y;
    }
#pragma unroll
    for (int k = 0; k < K; ++k) {
        const int id = tn_ids[b * K + k];
        float s = xx.x * Wp[(size_t)(2 * lane) * N_WORDS + id] +
                  xx.y * Wp[(size_t)(2 * lane + 1) * N_WORDS + id];
#pragma unroll
        for (int off = 32; off > 0; off >>= 1) s += __shfl_down(s, off, 64);
        if (lane == 0) out[b * K + k] = s;
    }
}

extern "C" void kernel_launch(void* const* d_in, const int* in_sizes, int n_in,
                              void* d_out, int out_size, void* d_ws, size_t ws_size,
                              hipStream_t stream) {
    const float* D  = (const float*)d_in[0];
    const float* W  = (const float*)d_in[1];
    const float* Wp = (const float*)d_in[2];
    const int* ctx  = (const int*)d_in[3];
    const int* doc  = (const int*)d_in[4];
    const int* tn   = (const int*)d_in[5];
    float* out = (float*)d_out;

    const size_t wpt_sz = (size_t)N_WORDS * EMB * sizeof(unsigned short);  // 25.6 MB
    const size_t x_off  = (wpt_sz + 255) & ~(size_t)255;
    const size_t need   = x_off + (size_t)BATCH * EMB * sizeof(float);     // + 8.4 MB

    if (ws_size >= need) {
        unsigned short* WpT = (unsigned short*)d_ws;
        float* x = (float*)((char*)d_ws + x_off);
        mega<<<TBLK + XBLK, 256, 0, stream>>>(Wp, WpT, D, W, ctx, doc, x);
        dotk<<<BATCH * K / 4, 256, 0, stream>>>(WpT, x, tn, out);
    } else {
        nce_direct<<<BATCH / 4, 256, 0, stream>>>(D, W, Wp, ctx, doc, tn, out);
    }
}

// Round 8
// 41.682 us; speedup vs baseline: 1.0784x; 1.0784x over previous
//
#include <hip/hip_runtime.h>

#define N_DOCS 500000
#define N_WORDS 100000
#define EMB 128
#define BATCH 16384
#define CTX 8
#define K 6
#define TW 256   // words per transpose tile
#define TD 32    // dims per transpose tile
#define NTB ((N_WORDS + TW - 1) / TW)  // 391

__device__ __forceinline__ unsigned short f2bf(float f) {
    unsigned u = __float_as_uint(f);
    unsigned r = u + 0x7fffu + ((u >> 16) & 1u);  // round-to-nearest-even
    return (unsigned short)(r >> 16);
}
#define BF2F(h) __uint_as_float(((unsigned)(h)) << 16)

// ---------------------------------------------------------------------------
// Transpose Wp [EMB, N_WORDS] f32 -> WpT [N_WORDS, EMB] bf16.
// 256-word x 32-dim tiles: reads are 1KB-contiguous per dim-row (16 cache
// lines), writes are full 64B lines per word. LDS [32][260] f32:
// read-phase ds_write_b128, write-phase column reads conflict-free.
// ---------------------------------------------------------------------------
__global__ __launch_bounds__(256) void transpose_bf16(const float* __restrict__ Wp,
                                                      unsigned short* __restrict__ WpT) {
    __shared__ float tile[TD][260];  // 260 = 256+4: row 16B-aligned, col reads conflict-free
    const int t = threadIdx.x;
    const int w0 = blockIdx.x * TW;      // word base
    const int d0 = blockIdx.y * TD;      // dim base

    // read: pass j covers rows 4j..4j+3; thread reads float4 of 4 words
    {
        const int wq = t & 63;           // word-quad index
        const int r0 = t >> 6;           // 0..3
        const int col = w0 + 4 * wq;
        if (col < N_WORDS) {             // N_WORDS%4==0 -> no straddle
#pragma unroll
            for (int j = 0; j < 8; ++j) {
                const int r = 4 * j + r0;
                const float4 v = *(const float4*)(Wp + (size_t)(d0 + r) * N_WORDS + col);
                *(float4*)&tile[r][4 * wq] = v;
            }
        }
    }
    __syncthreads();

    // write: thread t owns word w0+t; reads LDS column t (conflict-free),
    // packs 32 dims to bf16, stores 4x uint4 (full 64B line per word).
    const int w = w0 + t;
    if (w < N_WORDS) {
        float c[TD];
#pragma unroll
        for (int r = 0; r < TD; ++r) c[r] = tile[r][t];
        unsigned short* dst = WpT + (size_t)w * EMB + d0;
#pragma unroll
        for (int m = 0; m < 4; ++m) {
            uint4 o;
            o.x = (unsigned)f2bf(c[8 * m + 0]) | ((unsigned)f2bf(c[8 * m + 1]) << 16);
            o.y = (unsigned)f2bf(c[8 * m + 2]) | ((unsigned)f2bf(c[8 * m + 3]) << 16);
            o.z = (unsigned)f2bf(c[8 * m + 4]) | ((unsigned)f2bf(c[8 * m + 5]) << 16);
            o.w = (unsigned)f2bf(c[8 * m + 6]) | ((unsigned)f2bf(c[8 * m + 7]) << 16);
            *(uint4*)(dst + 8 * m) = o;
        }
    }
}

// ---------------------------------------------------------------------------
// Fused: one wave per b. x in registers; all 6 ids + 6 WpT rows prefetched
// (independent loads in flight), then 6 interleaved butterfly reduces.
// ---------------------------------------------------------------------------
__global__ __launch_bounds__(256) void nce_fused(const float* __restrict__ D,
                                                 const float* __restrict__ W,
                                                 const unsigned short* __restrict__ WpT,
                                                 const int* __restrict__ ctx_ids,
                                                 const int* __restrict__ doc_ids,
                                                 const int* __restrict__ tn_ids,
                                                 float* __restrict__ out) {
    const int lane = threadIdx.x & 63;
    const int b = __builtin_amdgcn_readfirstlane(blockIdx.x * 4 + (threadIdx.x >> 6));

    float2 xx = ((const float2*)(D + (size_t)doc_ids[b] * EMB))[lane];
#pragma unroll
    for (int c = 0; c < CTX; ++c) {
        const float2 w2 = ((const float2*)(W + (size_t)ctx_ids[b * CTX + c] * EMB))[lane];
        xx.x += w2.x;
        xx.y += w2.y;
    }

    int ids[K];
#pragma unroll
    for (int k = 0; k < K; ++k) ids[k] = tn_ids[b * K + k];
    ushort2 wv[K];
#pragma unroll
    for (int k = 0; k < K; ++k) wv[k] = ((const ushort2*)(WpT + (size_t)ids[k] * EMB))[lane];

    float s0 = xx.x * BF2F(wv[0].x) + xx.y * BF2F(wv[0].y);
    float s1 = xx.x * BF2F(wv[1].x) + xx.y * BF2F(wv[1].y);
    float s2 = xx.x * BF2F(wv[2].x) + xx.y * BF2F(wv[2].y);
    float s3 = xx.x * BF2F(wv[3].x) + xx.y * BF2F(wv[3].y);
    float s4 = xx.x * BF2F(wv[4].x) + xx.y * BF2F(wv[4].y);
    float s5 = xx.x * BF2F(wv[5].x) + xx.y * BF2F(wv[5].y);
#pragma unroll
    for (int off = 32; off > 0; off >>= 1) {
        s0 += __shfl_xor(s0, off, 64);
        s1 += __shfl_xor(s1, off, 64);
        s2 += __shfl_xor(s2, off, 64);
        s3 += __shfl_xor(s3, off, 64);
        s4 += __shfl_xor(s4, off, 64);
        s5 += __shfl_xor(s5, off, 64);
    }
    if (lane == 0) {
        float* o = out + b * K;
        *(float2*)(o + 0) = make_float2(s0, s1);
        *(float2*)(o + 2) = make_float2(s2, s3);
        *(float2*)(o + 4) = make_float2(s4, s5);
    }
}

// ---------------------------------------------------------------------------
// Fallback (no workspace): direct strided column gather.
// ---------------------------------------------------------------------------
__global__ __launch_bounds__(256) void nce_direct(
    const float* __restrict__ D, const float* __restrict__ W,
    const float* __restrict__ Wp, const int* __restrict__ ctx_ids,
    const int* __restrict__ doc_ids, const int* __restrict__ tn_ids,
    float* __restrict__ out) {
    const int wave = threadIdx.x >> 6, lane = threadIdx.x & 63;
    const int b = blockIdx.x * 4 + wave;
    if (b >= BATCH) return;
    float2 xx = ((const float2*)(D + (size_t)doc_ids[b] * EMB))[lane];
#pragma unroll
    for (int c = 0; c < CTX; ++c) {
        const float2 w2 = ((const float2*)(W + (size_t)ctx_ids[b * CTX + c] * EMB))[lane];
        xx.x += w2.x;
        xx.y += w2.y;
    }
#pragma unroll
    for (int k = 0; k < K; ++k) {
        const int id = tn_ids[b * K + k];
        float s = xx.x * Wp[(size_t)(2 * lane) * N_WORDS + id] +
                  xx.y * Wp[(size_t)(2 * lane + 1) * N_WORDS + id];
#pragma unroll
        for (int off = 32; off > 0; off >>= 1) s += __shfl_down(s, off, 64);
        if (lane == 0) out[b * K + k] = s;
    }
}

extern "C" void kernel_launch(void* const* d_in, const int* in_sizes, int n_in,
                              void* d_out, int out_size, void* d_ws, size_t ws_size,
                              hipStream_t stream) {
    const float* D  = (const float*)d_in[0];
    const float* W  = (const float*)d_in[1];
    const float* Wp = (const float*)d_in[2];
    const int* ctx  = (const int*)d_in[3];
    const int* doc  = (const int*)d_in[4];
    const int* tn   = (const int*)d_in[5];
    float* out = (float*)d_out;

    const size_t need = (size_t)N_WORDS * EMB * sizeof(unsigned short);  // 25.6 MB
    if (ws_size >= need) {
        unsigned short* WpT = (unsigned short*)d_ws;
        transpose_bf16<<<dim3(NTB, EMB / TD), 256, 0, stream>>>(Wp, WpT);
        nce_fused<<<BATCH / 4, 256, 0, stream>>>(D, W, WpT, ctx, doc, tn, out);
    } else {
        nce_direct<<<BATCH / 4, 256, 0, stream>>>(D, W, Wp, ctx, doc, tn, out);
    }
}

// Round 9
// 36.166 us; speedup vs baseline: 1.2429x; 1.1525x over previous
//
#include <hip/hip_runtime.h>

#define N_DOCS 500000
#define N_WORDS 100000
#define EMB 128
#define BATCH 16384
#define CTX 8
#define K 6
#define TW 64
#define LSTRIDE 67  // f32 LDS row stride: write-phase <=4-way, read-phase <=2-way banks
#define NTB ((N_WORDS + TW - 1) / TW)  // 1563

__device__ __forceinline__ unsigned f2bf(float f) {
    unsigned u = __float_as_uint(f);
    unsigned r = u + 0x7fffu + ((u >> 16) & 1u);  // round-to-nearest-even
    return r >> 16;
}
#define BF2F(h) __uint_as_float(((unsigned)(h)) << 16)

// ---------------------------------------------------------------------------
// Transpose Wp [EMB, N_WORDS] f32 -> WpT [N_WORDS, EMB] bf16.
// 64-word x 128-dim tile. Every global wave-instruction is 1KB contiguous:
// reads = 4 rows x 256B float4 segments; writes = byte offset base + 16*t.
// ---------------------------------------------------------------------------
__global__ __launch_bounds__(256) void transpose_bf16(const float* __restrict__ Wp,
                                                      unsigned short* __restrict__ WpT) {
    __shared__ float tile[EMB * LSTRIDE];
    const int t = threadIdx.x;
    const int w0 = blockIdx.x * TW;

    // read phase: thread (fq, e0) loads float4 of words w0+4fq.. for dims e0+16j
    {
        const int fq = t & 15, e0 = t >> 4;
        const int col = w0 + 4 * fq;
        if (col + 3 < N_WORDS) {
#pragma unroll
            for (int j = 0; j < 8; ++j) {
                const int e = e0 + 16 * j;
                const float4 v = *(const float4*)(Wp + (size_t)e * N_WORDS + col);
                float* d = &tile[e * LSTRIDE + 4 * fq];
                d[0] = v.x; d[1] = v.y; d[2] = v.z; d[3] = v.w;
            }
        }
    }
    __syncthreads();

    // write phase: pass r -> block writes 16KB contiguous (wave-instr = 1KB).
    // thread t: word 16r+(t>>4), dims 8(t&15)..+7 packed to one uint4.
#pragma unroll
    for (int r = 0; r < 4; ++r) {
        const int wl = 16 * r + (t >> 4);
        const int w = w0 + wl;
        if (w < N_WORDS) {
            const int db = 8 * (t & 15);
            float c[8];
#pragma unroll
            for (int j = 0; j < 8; ++j) c[j] = tile[(db + j) * LSTRIDE + wl];
            uint4 o;
            o.x = f2bf(c[0]) | (f2bf(c[1]) << 16);
            o.y = f2bf(c[2]) | (f2bf(c[3]) << 16);
            o.z = f2bf(c[4]) | (f2bf(c[5]) << 16);
            o.w = f2bf(c[6]) | (f2bf(c[7]) << 16);
            *(uint4*)(WpT + (size_t)w * EMB + db) = o;
        }
    }
}

// ---------------------------------------------------------------------------
// Fused (exactly round-6): one wave per b; b wave-uniform via readfirstlane
// so index loads are scalar; lane l holds dims {2l, 2l+1}.
// ---------------------------------------------------------------------------
__global__ __launch_bounds__(256) void nce_fused(const float* __restrict__ D,
                                                 const float* __restrict__ W,
                                                 const unsigned short* __restrict__ WpT,
                                                 const int* __restrict__ ctx_ids,
                                                 const int* __restrict__ doc_ids,
                                                 const int* __restrict__ tn_ids,
                                                 float* __restrict__ out) {
    const int lane = threadIdx.x & 63;
    const int b = __builtin_amdgcn_readfirstlane(blockIdx.x * 4 + (threadIdx.x >> 6));

    const int doc = doc_ids[b];
    float2 xx = ((const float2*)(D + (size_t)doc * EMB))[lane];
#pragma unroll
    for (int c = 0; c < CTX; ++c) {
        const int id = ctx_ids[b * CTX + c];
        const float2 w2 = ((const float2*)(W + (size_t)id * EMB))[lane];
        xx.x += w2.x;
        xx.y += w2.y;
    }

#pragma unroll
    for (int k = 0; k < K; ++k) {
        const int id = tn_ids[b * K + k];
        const ushort2 w2 = ((const ushort2*)(WpT + (size_t)id * EMB))[lane];
        float s = xx.x * BF2F(w2.x) + xx.y * BF2F(w2.y);
#pragma unroll
        for (int off = 32; off > 0; off >>= 1) s += __shfl_xor(s, off, 64);
        if (lane == 0) out[b * K + k] = s;
    }
}

// ---------------------------------------------------------------------------
// Fallback (no workspace): direct strided column gather.
// ---------------------------------------------------------------------------
__global__ __launch_bounds__(256) void nce_direct(
    const float* __restrict__ D, const float* __restrict__ W,
    const float* __restrict__ Wp, const int* __restrict__ ctx_ids,
    const int* __restrict__ doc_ids, const int* __restrict__ tn_ids,
    float* __restrict__ out) {
    const int wave = threadIdx.x >> 6, lane = threadIdx.x & 63;
    const int b = blockIdx.x * 4 + wave;
    if (b >= BATCH) return;
    float2 xx = ((const float2*)(D + (size_t)doc_ids[b] * EMB))[lane];
#pragma unroll
    for (int c = 0; c < CTX; ++c) {
        const float2 w2 = ((const float2*)(W + (size_t)ctx_ids[b * CTX + c] * EMB))[lane];
        xx.x += w2.x;
        xx.y += w2.y;
    }
#pragma unroll
    for (int k = 0; k < K; ++k) {
        const int id = tn_ids[b * K + k];
        float s = xx.x * Wp[(size_t)(2 * lane) * N_WORDS + id] +
                  xx.y * Wp[(size_t)(2 * lane + 1) * N_WORDS + id];
#pragma unroll
        for (int off = 32; off > 0; off >>= 1) s += __shfl_down(s, off, 64);
        if (lane == 0) out[b * K + k] = s;
    }
}

extern "C" void kernel_launch(void* const* d_in, const int* in_sizes, int n_in,
                              void* d_out, int out_size, void* d_ws, size_t ws_size,
                              hipStream_t stream) {
    const float* D  = (const float*)d_in[0];
    const float* W  = (const float*)d_in[1];
    const float* Wp = (const float*)d_in[2];
    const int* ctx  = (const int*)d_in[3];
    const int* doc  = (const int*)d_in[4];
    const int* tn   = (const int*)d_in[5];
    float* out = (float*)d_out;

    const size_t need = (size_t)N_WORDS * EMB * sizeof(unsigned short);  // 25.6 MB
    if (ws_size >= need) {
        unsigned short* WpT = (unsigned short*)d_ws;
        transpose_bf16<<<NTB, 256, 0, stream>>>(Wp, WpT);
        nce_fused<<<BATCH / 4, 256, 0, stream>>>(D, W, WpT, ctx, doc, tn, out);
    } else {
        nce_direct<<<BATCH / 4, 256, 0, stream>>>(D, W, Wp, ctx, doc, tn, out);
    }
}

// Round 10
// 34.259 us; speedup vs baseline: 1.3120x; 1.0556x over previous
//
#include <hip/hip_runtime.h>

#define N_DOCS 500000
#define N_WORDS 100000
#define EMB 128
#define BATCH 16384
#define CTX 8
#define K 6
#define TW 64
#define LSTRIDE 67  // f32 LDS row stride: write-phase <=4-way, read-phase <=2-way banks
#define NTB ((N_WORDS + TW - 1) / TW)  // 1563

__device__ __forceinline__ unsigned f2bf(float f) {
    unsigned u = __float_as_uint(f);
    unsigned r = u + 0x7fffu + ((u >> 16) & 1u);  // round-to-nearest-even
    return r >> 16;
}
#define BF2F(h) __uint_as_float(((unsigned)(h)) << 16)

// ---------------------------------------------------------------------------
// Transpose Wp [EMB, N_WORDS] f32 -> WpT [N_WORDS, EMB] bf16 (round-9, at BW floor).
// ---------------------------------------------------------------------------
__global__ __launch_bounds__(256) void transpose_bf16(const float* __restrict__ Wp,
                                                      unsigned short* __restrict__ WpT) {
    __shared__ float tile[EMB * LSTRIDE];
    const int t = threadIdx.x;
    const int w0 = blockIdx.x * TW;

    {
        const int fq = t & 15, e0 = t >> 4;
        const int col = w0 + 4 * fq;
        if (col + 3 < N_WORDS) {
#pragma unroll
            for (int j = 0; j < 8; ++j) {
                const int e = e0 + 16 * j;
                const float4 v = *(const float4*)(Wp + (size_t)e * N_WORDS + col);
                float* d = &tile[e * LSTRIDE + 4 * fq];
                d[0] = v.x; d[1] = v.y; d[2] = v.z; d[3] = v.w;
            }
        }
    }
    __syncthreads();

#pragma unroll
    for (int r = 0; r < 4; ++r) {
        const int wl = 16 * r + (t >> 4);
        const int w = w0 + wl;
        if (w < N_WORDS) {
            const int db = 8 * (t & 15);
            float c[8];
#pragma unroll
            for (int j = 0; j < 8; ++j) c[j] = tile[(db + j) * LSTRIDE + wl];
            uint4 o;
            o.x = f2bf(c[0]) | (f2bf(c[1]) << 16);
            o.y = f2bf(c[2]) | (f2bf(c[3]) << 16);
            o.z = f2bf(c[4]) | (f2bf(c[5]) << 16);
            o.w = f2bf(c[6]) | (f2bf(c[7]) << 16);
            *(uint4*)(WpT + (size_t)w * EMB + db) = o;
        }
    }
}

// ---------------------------------------------------------------------------
// Fused v2: quarter-wave (16 lanes x 8 dims) per b, 4 b's per wave, 16 b's
// per block. All gathers independent & in flight together; 4-step reduce.
// ---------------------------------------------------------------------------
__global__ __launch_bounds__(256) void nce_fused4(const float* __restrict__ D,
                                                  const float* __restrict__ W,
                                                  const unsigned short* __restrict__ WpT,
                                                  const int* __restrict__ ctx_ids,
                                                  const int* __restrict__ doc_ids,
                                                  const int* __restrict__ tn_ids,
                                                  float* __restrict__ out) {
    const int t = threadIdx.x;
    const int lane = t & 63;
    const int li = lane & 15;                    // lane within quarter
    const int b = blockIdx.x * 16 + (t >> 6) * 4 + (lane >> 4);

    // ids: per-quarter uniform addresses -> hardware broadcast loads
    const int doc = doc_ids[b];
    int cids[CTX];
#pragma unroll
    for (int c = 0; c < CTX; ++c) cids[c] = ctx_ids[b * CTX + c];
    int ids[K];
#pragma unroll
    for (int k = 0; k < K; ++k) ids[k] = tn_ids[b * K + k];

    // x phase: dims li*8 .. li*8+7 in registers
    const float* Dr = D + (size_t)doc * EMB + li * 8;
    float4 a0 = *(const float4*)Dr;
    float4 a1 = *(const float4*)(Dr + 4);
#pragma unroll
    for (int c = 0; c < CTX; ++c) {
        const float* Wr = W + (size_t)cids[c] * EMB + li * 8;
        const float4 w0 = *(const float4*)Wr;
        const float4 w1 = *(const float4*)(Wr + 4);
        a0.x += w0.x; a0.y += w0.y; a0.z += w0.z; a0.w += w0.w;
        a1.x += w1.x; a1.y += w1.y; a1.z += w1.z; a1.w += w1.w;
    }

    // dot phase: prefetch all 6 WpT fragments, then reduce
    uint4 wf[K];
#pragma unroll
    for (int k = 0; k < K; ++k)
        wf[k] = *(const uint4*)(WpT + (size_t)ids[k] * EMB + li * 8);

#pragma unroll
    for (int k = 0; k < K; ++k) {
        const uint4 u = wf[k];
        float s = BF2F(u.x & 0xffff) * a0.x + BF2F(u.x >> 16) * a0.y +
                  BF2F(u.y & 0xffff) * a0.z + BF2F(u.y >> 16) * a0.w +
                  BF2F(u.z & 0xffff) * a1.x + BF2F(u.z >> 16) * a1.y +
                  BF2F(u.w & 0xffff) * a1.z + BF2F(u.w >> 16) * a1.w;
        s += __shfl_xor(s, 8, 64);
        s += __shfl_xor(s, 4, 64);
        s += __shfl_xor(s, 2, 64);
        s += __shfl_xor(s, 1, 64);
        if (li == 0) out[b * K + k] = s;
    }
}

// ---------------------------------------------------------------------------
// Fallback (no workspace): direct strided column gather.
// ---------------------------------------------------------------------------
__global__ __launch_bounds__(256) void nce_direct(
    const float* __restrict__ D, const float* __restrict__ W,
    const float* __restrict__ Wp, const int* __restrict__ ctx_ids,
    const int* __restrict__ doc_ids, const int* __restrict__ tn_ids,
    float* __restrict__ out) {
    const int wave = threadIdx.x >> 6, lane = threadIdx.x & 63;
    const int b = blockIdx.x * 4 + wave;
    if (b >= BATCH) return;
    float2 xx = ((const float2*)(D + (size_t)doc_ids[b] * EMB))[lane];
#pragma unroll
    for (int c = 0; c < CTX; ++c) {
        const float2 w2 = ((const float2*)(W + (size_t)ctx_ids[b * CTX + c] * EMB))[lane];
        xx.x += w2.x;
        xx.y += w2.y;
    }
#pragma unroll
    for (int k = 0; k < K; ++k) {
        const int id = tn_ids[b * K + k];
        float s = xx.x * Wp[(size_t)(2 * lane) * N_WORDS + id] +
                  xx.y * Wp[(size_t)(2 * lane + 1) * N_WORDS + id];
#pragma unroll
        for (int off = 32; off > 0; off >>= 1) s += __shfl_down(s, off, 64);
        if (lane == 0) out[b * K + k] = s;
    }
}

extern "C" void kernel_launch(void* const* d_in, const int* in_sizes, int n_in,
                              void* d_out, int out_size, void* d_ws, size_t ws_size,
                              hipStream_t stream) {
    const float* D  = (const float*)d_in[0];
    const float* W  = (const float*)d_in[1];
    const float* Wp = (const float*)d_in[2];
    const int* ctx  = (const int*)d_in[3];
    const int* doc  = (const int*)d_in[4];
    const int* tn   = (const int*)d_in[5];
    float* out = (float*)d_out;

    const size_t need = (size_t)N_WORDS * EMB * sizeof(unsigned short);  // 25.6 MB
    if (ws_size >= need) {
        unsigned short* WpT = (unsigned short*)d_ws;
        transpose_bf16<<<NTB, 256, 0, stream>>>(Wp, WpT);
        nce_fused4<<<BATCH / 16, 256, 0, stream>>>(D, W, WpT, ctx, doc, tn, out);
    } else {
        nce_direct<<<BATCH / 4, 256, 0, stream>>>(D, W, Wp, ctx, doc, tn, out);
    }
}